// Round 6
// baseline (2430.199 us; speedup 1.0000x reference)
//
#include <hip/hip_runtime.h>
#include <stdint.h>

#define N_SIZE 4096
#define N_STEPS 512
#define WROW 8192
#define THRESH 10.0f

#define WST_BYTES ((size_t)(N_SIZE + 1) * N_SIZE * 4)   // WsT + zero pad row

#define F4E(v, j) ((j) == 0 ? (v).x : (j) == 1 ? (v).y : (j) == 2 ? (v).z : (v).w)
#define ADD4(a, b) { (a).x += (b).x; (a).y += (b).y; (a).z += (b).z; (a).w += (b).w; }

// ---------------- transpose: WsT[s][o] = W[o*8192 + 4096 + s] ----------------
__global__ __launch_bounds__(256) void k_transpose(const float* __restrict__ W,
                                                   float* __restrict__ WsT) {
    __shared__ float tile[32][33];
    const int bs = blockIdx.x * 32;
    const int bo = blockIdx.y * 32;
    const int tx = threadIdx.x;
    const int ty = threadIdx.y;
#pragma unroll
    for (int j = 0; j < 4; ++j)
        tile[ty + j * 8][tx] = W[(size_t)(bo + ty + j * 8) * WROW + N_SIZE + bs + tx];
    __syncthreads();
#pragma unroll
    for (int j = 0; j < 4; ++j)
        WsT[(size_t)(bs + ty + j * 8) * N_SIZE + bo + tx] = tile[tx][ty + j * 8];
}

// ---------------- zero the pad row (every launch; ws is poisoned once) ------
__global__ __launch_bounds__(256) void k_zero_row(float* __restrict__ WsT) {
    WsT[(size_t)N_SIZE * N_SIZE + blockIdx.x * 256 + threadIdx.x] = 0.f;
}

// ---------------- GEMM: C[t][o] = sum_k x[t][k] * W[o][k], split-K=2 --------
#define BM 64
#define BN 128
#define BK 16
#define KHALF (N_SIZE / 2)
#define ALD 68
#define BLD 132

__global__ __launch_bounds__(128) void k_gemm(const float* __restrict__ x,
                                              const float* __restrict__ W,
                                              float* __restrict__ dst0,
                                              float* __restrict__ dst1) {
    __shared__ float As[BK][ALD];
    __shared__ float Bs[BK][BLD];
    const int tid = threadIdx.x;
    const int bm = blockIdx.y * BM;
    const int bn = blockIdx.x * BN;
    const int kb0 = blockIdx.z * KHALF;
    float* dst = blockIdx.z ? dst1 : dst0;

    const int m0 = (tid >> 4) << 3;
    const int n0 = (tid & 15) << 2;
    const int ar = tid >> 2;
    const int ac = (tid & 3) << 2;
    const float* Ap = &x[(size_t)(bm + ar) * N_SIZE + kb0 + ac];
    const float* Bp = &W[(size_t)(bn + ar) * WROW + kb0 + ac];

    float4 pa0 = *(const float4*)&Ap[0];
    float4 pa1 = *(const float4*)&Ap[(size_t)32 * N_SIZE];
    float4 pb0 = *(const float4*)&Bp[0];
    float4 pb1 = *(const float4*)&Bp[(size_t)32 * WROW];
    float4 pb2 = *(const float4*)&Bp[(size_t)64 * WROW];
    float4 pb3 = *(const float4*)&Bp[(size_t)96 * WROW];

    float acc[8][8];
#pragma unroll
    for (int i = 0; i < 8; ++i)
#pragma unroll
        for (int j = 0; j < 8; ++j) acc[i][j] = 0.f;

    const int nkt = KHALF / BK;
    for (int kt = 0; kt < nkt; ++kt) {
        __syncthreads();
#pragma unroll
        for (int j = 0; j < 4; ++j) {
            As[ac + j][ar]      = F4E(pa0, j);
            As[ac + j][ar + 32] = F4E(pa1, j);
            Bs[ac + j][ar]      = F4E(pb0, j);
            Bs[ac + j][ar + 32] = F4E(pb1, j);
            Bs[ac + j][ar + 64] = F4E(pb2, j);
            Bs[ac + j][ar + 96] = F4E(pb3, j);
        }
        __syncthreads();
        if (kt + 1 < nkt) {
            const float* Ap2 = Ap + (size_t)(kt + 1) * BK;
            const float* Bp2 = Bp + (size_t)(kt + 1) * BK;
            pa0 = *(const float4*)&Ap2[0];
            pa1 = *(const float4*)&Ap2[(size_t)32 * N_SIZE];
            pb0 = *(const float4*)&Bp2[0];
            pb1 = *(const float4*)&Bp2[(size_t)32 * WROW];
            pb2 = *(const float4*)&Bp2[(size_t)64 * WROW];
            pb3 = *(const float4*)&Bp2[(size_t)96 * WROW];
        }
#pragma unroll
        for (int k = 0; k < BK; ++k) {
            const float4 a0 = *(const float4*)&As[k][m0];
            const float4 a1 = *(const float4*)&As[k][m0 + 4];
            const float4 b0 = *(const float4*)&Bs[k][n0];
            const float4 b1 = *(const float4*)&Bs[k][n0 + 64];
            const float av[8] = {a0.x, a0.y, a0.z, a0.w, a1.x, a1.y, a1.z, a1.w};
            const float bv[8] = {b0.x, b0.y, b0.z, b0.w, b1.x, b1.y, b1.z, b1.w};
#pragma unroll
            for (int i = 0; i < 8; ++i)
#pragma unroll
                for (int j = 0; j < 8; ++j)
                    acc[i][j] = fmaf(av[i], bv[j], acc[i][j]);
        }
    }
#pragma unroll
    for (int i = 0; i < 8; ++i) {
        float* cp = &dst[(size_t)(bm + m0 + i) * N_SIZE + bn];
        const float4 o0 = {acc[i][0], acc[i][1], acc[i][2], acc[i][3]};
        const float4 o1 = {acc[i][4], acc[i][5], acc[i][6], acc[i][7]};
        *(float4*)&cp[n0] = o0;
        *(float4*)&cp[n0 + 64] = o1;
    }
}

__global__ __launch_bounds__(256) void k_reduce(float* __restrict__ acc,
                                                const float* __restrict__ part) {
    const size_t i = ((size_t)blockIdx.x * 256 + threadIdx.x) * 4;
    const float4 a = *(const float4*)&acc[i];
    const float4 b = *(const float4*)&part[i];
    const float4 r = {a.x + b.x, a.y + b.y, a.z + b.z, a.w + b.w};
    *(float4*)&acc[i] = r;
}

// ---------------- single-WG scan, NO per-step __syncthreads ----------------
// 4 waves (one per SIMD) x 64 lanes x 16 neurons. Waves sync via LDS
// monotonic counters: relaxed ds-atomics + explicit lgkmcnt(0) ordering of
// LDS-only data. Global stores (spk/mem rows) and the cur_x prefetch are
// NEVER drained by a barrier -> the per-step critical path is one gather
// round + two LDS poll rounds. Deterministic ascending-neuron sum order.
// Skew proof: a wave reaches its step-t+1 wq write only after passing the
// step-t cntB poll, which requires every wave to have finished reading wq
// (phase A) and the step-t-1 list buffer (gather) -> no overwrite races.
__global__ __launch_bounds__(256, 1) void k_scanW(const float* __restrict__ WsT,
                                                  float* __restrict__ spk_out,
                                                  float* __restrict__ mem_out) {
    __shared__ int lst[2][N_SIZE + 8];
    __shared__ int wq[4];
    __shared__ unsigned cntA, cntB;
    const int tid = threadIdx.x;
    const int wave = tid >> 6;
    const int lane = tid & 63;
    const int base = tid << 4;          // neurons base..base+15 (contiguous)
    const unsigned long long below = (lane == 0) ? 0ULL : (~0ULL >> (64 - lane));

    if (tid == 0) { cntA = 0u; cntB = 0u; }
    __syncthreads();                    // one-time init barrier only

    float4 mem[4];
#pragma unroll
    for (int q = 0; q < 4; ++q) mem[q] = {0.f, 0.f, 0.f, 0.f};
    int tot = 0;

    float4 cn[4];
#pragma unroll
    for (int q = 0; q < 4; ++q)
        cn[q] = *(const float4*)&mem_out[base + q * 4];

    for (int t = 0; t < N_STEPS; ++t) {
        const int par = t & 1;
        float4 c[4];
#pragma unroll
        for (int q = 0; q < 4; ++q) c[q] = cn[q];

        // prefetch next cur_x row; no barrier will ever drain it
        const int tn = (t + 1 < N_STEPS) ? (t + 1) : t;
        const float* nr = &mem_out[(size_t)tn * N_SIZE + base];
#pragma unroll
        for (int q = 0; q < 4; ++q) cn[q] = *(const float4*)&nr[q * 4];

        // ---- gather: 8 columns per chunk, all 32 float4 loads in flight ----
        const int* lp = lst[par];
        for (int i0 = 0; i0 < tot; i0 += 8) {
            const int4 ia = *(const int4*)&lp[i0];
            const int4 ib = *(const int4*)&lp[i0 + 4];
            const int sx[8] = {ia.x, ia.y, ia.z, ia.w, ib.x, ib.y, ib.z, ib.w};
            float4 v[8][4];
#pragma unroll
            for (int j = 0; j < 8; ++j) {
                const int s = __builtin_amdgcn_readfirstlane(sx[j]);
                const float* p = WsT + s * N_SIZE + base;
#pragma unroll
                for (int q = 0; q < 4; ++q)
                    v[j][q] = *(const float4*)&p[q * 4];
            }
#pragma unroll
            for (int j = 0; j < 8; ++j)
#pragma unroll
                for (int q = 0; q < 4; ++q)
                    ADD4(c[q], v[j][q])
        }

        // ---- membrane update, threshold ----
        bool sb[16];
#pragma unroll
        for (int q = 0; q < 4; ++q) {
            ADD4(mem[q], c[q])
            sb[q * 4 + 0] = mem[q].x > THRESH;
            sb[q * 4 + 1] = mem[q].y > THRESH;
            sb[q * 4 + 2] = mem[q].z > THRESH;
            sb[q * 4 + 3] = mem[q].w > THRESH;
            mem[q].x -= sb[q * 4 + 0] ? THRESH : 0.f;
            mem[q].y -= sb[q * 4 + 1] ? THRESH : 0.f;
            mem[q].z -= sb[q * 4 + 2] ? THRESH : 0.f;
            mem[q].w -= sb[q * 4 + 3] ? THRESH : 0.f;
        }

        // ---- outputs: fire-and-forget, never drained ----
        float* srow = &spk_out[(size_t)t * N_SIZE + base];
        float* mrow = &mem_out[(size_t)t * N_SIZE + base];
#pragma unroll
        for (int q = 0; q < 4; ++q) {
            const float4 sp = {sb[q * 4 + 0] ? 1.f : 0.f, sb[q * 4 + 1] ? 1.f : 0.f,
                               sb[q * 4 + 2] ? 1.f : 0.f, sb[q * 4 + 3] ? 1.f : 0.f};
            *(float4*)&srow[q * 4] = sp;
            *(float4*)&mrow[q * 4] = mem[q];
        }

        // ---- ballots ----
        int pre = 0, wtot = 0;
#pragma unroll
        for (int j = 0; j < 16; ++j) {
            const unsigned long long B = __ballot(sb[j]);
            pre += __popcll(B & below);
            wtot += __popcll(B);
        }

        const unsigned tgt = 4u * (unsigned)(t + 1);

        // ---- phase A: publish count, poll all counts (LDS-only ordering) ----
        if (lane == 0) {
            wq[wave] = wtot;
            asm volatile("s_waitcnt lgkmcnt(0)" ::: "memory");
            __hip_atomic_fetch_add(&cntA, 1u, __ATOMIC_RELAXED,
                                   __HIP_MEMORY_SCOPE_WORKGROUP);
        }
        while (__hip_atomic_load(&cntA, __ATOMIC_RELAXED,
                                 __HIP_MEMORY_SCOPE_WORKGROUP) < tgt)
            __builtin_amdgcn_s_sleep(1);
        asm volatile("" ::: "memory");

        int woff = 0, tt = 0;
#pragma unroll
        for (int w = 0; w < 4; ++w) {
            const int cw = wq[w];
            if (w < wave) woff += cw;
            tt += cw;
        }

        // ---- phase B: write own sorted segment + pads, poll ----
        int* nxt = lst[par ^ 1];
        int off = woff + pre;
#pragma unroll
        for (int j = 0; j < 16; ++j)
            if (sb[j]) nxt[off++] = base + j;
        if (wave == 0 && lane < 8) nxt[tt + lane] = N_SIZE;   // pad -> zero row
        if (lane == 0) {
            asm volatile("s_waitcnt lgkmcnt(0)" ::: "memory");
            __hip_atomic_fetch_add(&cntB, 1u, __ATOMIC_RELAXED,
                                   __HIP_MEMORY_SCOPE_WORKGROUP);
        }
        while (__hip_atomic_load(&cntB, __ATOMIC_RELAXED,
                                 __HIP_MEMORY_SCOPE_WORKGROUP) < tgt)
            __builtin_amdgcn_s_sleep(1);
        asm volatile("" ::: "memory");

        tot = tt;
    }
}

// ---------------- fallback: single-WG scan (no/partial ws) ----------------
template <int USE_WST>
__global__ __launch_bounds__(1024) void k_scan1(const float* __restrict__ WsT,
                                                const float* __restrict__ W,
                                                float* __restrict__ spk_out,
                                                float* __restrict__ mem_out) {
    __shared__ int lists[2][N_SIZE];
    __shared__ int wcnt[16];
    const int tid = threadIdx.x;
    const int wave = tid >> 6;
    const int lane = tid & 63;
    const int base = tid << 2;
    const unsigned long long below = (lane == 0) ? 0ULL : (~0ULL >> (64 - lane));

    float4 mem = {0.f, 0.f, 0.f, 0.f};
    int cnt = 0, cur = 0;
    for (int t = 0; t < N_STEPS; ++t) {
        float* mrow = &mem_out[(size_t)t * N_SIZE + base];
        float4 c = *(const float4*)mrow;
        const int* lstp = lists[cur];
        for (int i = 0; i < cnt; ++i) {
            const int s = lstp[i];
            float4 w0;
            if (USE_WST) {
                w0 = *(const float4*)&WsT[(size_t)s * N_SIZE + base];
            } else {
                w0.x = W[(size_t)(base + 0) * WROW + N_SIZE + s];
                w0.y = W[(size_t)(base + 1) * WROW + N_SIZE + s];
                w0.z = W[(size_t)(base + 2) * WROW + N_SIZE + s];
                w0.w = W[(size_t)(base + 3) * WROW + N_SIZE + s];
            }
            ADD4(c, w0)
        }
        ADD4(mem, c)
        const bool s0 = mem.x > THRESH, s1 = mem.y > THRESH;
        const bool s2 = mem.z > THRESH, s3 = mem.w > THRESH;
        mem.x -= s0 ? THRESH : 0.f;  mem.y -= s1 ? THRESH : 0.f;
        mem.z -= s2 ? THRESH : 0.f;  mem.w -= s3 ? THRESH : 0.f;
        const float4 spkv = {s0 ? 1.f : 0.f, s1 ? 1.f : 0.f,
                             s2 ? 1.f : 0.f, s3 ? 1.f : 0.f};
        *(float4*)&spk_out[(size_t)t * N_SIZE + base] = spkv;
        *(float4*)mrow = mem;
        const unsigned long long b0 = __ballot(s0), b1 = __ballot(s1);
        const unsigned long long b2 = __ballot(s2), b3 = __ballot(s3);
        const int pre = __popcll(b0 & below) + __popcll(b1 & below) +
                        __popcll(b2 & below) + __popcll(b3 & below);
        if (lane == 0)
            wcnt[wave] = __popcll(b0) + __popcll(b1) + __popcll(b2) + __popcll(b3);
        __syncthreads();
        int woff = 0, total = 0;
#pragma unroll
        for (int wv = 0; wv < 16; ++wv) {
            const int cw = wcnt[wv];
            if (wv < wave) woff += cw;
            total += cw;
        }
        int* nxt = lists[cur ^ 1];
        int off = woff + pre;
        if (s0) nxt[off++] = base;
        if (s1) nxt[off++] = base + 1;
        if (s2) nxt[off++] = base + 2;
        if (s3) nxt[off++] = base + 3;
        __syncthreads();
        cnt = total;
        cur ^= 1;
    }
}

extern "C" void kernel_launch(void* const* d_in, const int* in_sizes, int n_in,
                              void* d_out, int out_size, void* d_ws, size_t ws_size,
                              hipStream_t stream) {
    const float* x = (const float*)d_in[0];
    const float* W = (const float*)d_in[1];
    float* spk_out = (float*)d_out;
    float* mem_out = spk_out + (size_t)N_STEPS * N_SIZE;
    float* WsT = (float*)d_ws;
    const bool full = ws_size >= WST_BYTES;
    const bool use_wst = ws_size >= (size_t)N_SIZE * N_SIZE * 4;

    if (full) {
        k_zero_row<<<16, 256, 0, stream>>>(WsT);
        k_transpose<<<dim3(N_SIZE / 32, N_SIZE / 32), dim3(32, 8), 0, stream>>>(W, WsT);
    } else if (use_wst) {
        k_transpose<<<dim3(N_SIZE / 32, N_SIZE / 32), dim3(32, 8), 0, stream>>>(W, WsT);
    }

    k_gemm<<<dim3(N_SIZE / BN, N_STEPS / BM, 2), 128, 0, stream>>>(x, W, mem_out, spk_out);
    k_reduce<<<(N_STEPS * N_SIZE) / (256 * 4), 256, 0, stream>>>(mem_out, spk_out);

    if (full) {
        k_scanW<<<1, 256, 0, stream>>>(WsT, spk_out, mem_out);
    } else if (use_wst) {
        k_scan1<1><<<1, 1024, 0, stream>>>(WsT, W, spk_out, mem_out);
    } else {
        k_scan1<0><<<1, 1024, 0, stream>>>(WsT, W, spk_out, mem_out);
    }
}

// Round 7
// 1932.992 us; speedup vs baseline: 1.2572x; 1.2572x over previous
//
#include <hip/hip_runtime.h>
#include <stdint.h>

#define N_SIZE 4096
#define N_STEPS 512
#define WROW 8192
#define THRESH 10.0f

#define WST_BYTES ((size_t)(N_SIZE + 1) * N_SIZE * 4)   // WsT + zero pad row

typedef float f32x4 __attribute__((ext_vector_type(4)));
typedef int   i32x4 __attribute__((ext_vector_type(4)));

#define F4E(v, j) ((j) == 0 ? (v).x : (j) == 1 ? (v).y : (j) == 2 ? (v).z : (v).w)
#define ADD4(a, b) { (a).x += (b).x; (a).y += (b).y; (a).z += (b).z; (a).w += (b).w; }

// ---------------- transpose: WsT[s][o] = W[o*8192 + 4096 + s] ----------------
__global__ __launch_bounds__(256) void k_transpose(const float* __restrict__ W,
                                                   float* __restrict__ WsT) {
    __shared__ float tile[32][33];
    const int bs = blockIdx.x * 32;
    const int bo = blockIdx.y * 32;
    const int tx = threadIdx.x;
    const int ty = threadIdx.y;
#pragma unroll
    for (int j = 0; j < 4; ++j)
        tile[ty + j * 8][tx] = W[(size_t)(bo + ty + j * 8) * WROW + N_SIZE + bs + tx];
    __syncthreads();
#pragma unroll
    for (int j = 0; j < 4; ++j)
        WsT[(size_t)(bs + ty + j * 8) * N_SIZE + bo + tx] = tile[tx][ty + j * 8];
}

// ---------------- zero the pad row (every launch; ws is poisoned once) ------
__global__ __launch_bounds__(256) void k_zero_row(float* __restrict__ WsT) {
    WsT[(size_t)N_SIZE * N_SIZE + blockIdx.x * 256 + threadIdx.x] = 0.f;
}

// ---------------- GEMM: C[t][o] = sum_k x[t][k] * W[o][k], split-K=2 --------
#define BM 64
#define BN 128
#define BK 16
#define KHALF (N_SIZE / 2)
#define ALD 68
#define BLD 132

__global__ __launch_bounds__(128) void k_gemm(const float* __restrict__ x,
                                              const float* __restrict__ W,
                                              float* __restrict__ dst0,
                                              float* __restrict__ dst1) {
    __shared__ float As[BK][ALD];
    __shared__ float Bs[BK][BLD];
    const int tid = threadIdx.x;
    const int bm = blockIdx.y * BM;
    const int bn = blockIdx.x * BN;
    const int kb0 = blockIdx.z * KHALF;
    float* dst = blockIdx.z ? dst1 : dst0;

    const int m0 = (tid >> 4) << 3;
    const int n0 = (tid & 15) << 2;
    const int ar = tid >> 2;
    const int ac = (tid & 3) << 2;
    const float* Ap = &x[(size_t)(bm + ar) * N_SIZE + kb0 + ac];
    const float* Bp = &W[(size_t)(bn + ar) * WROW + kb0 + ac];

    float4 pa0 = *(const float4*)&Ap[0];
    float4 pa1 = *(const float4*)&Ap[(size_t)32 * N_SIZE];
    float4 pb0 = *(const float4*)&Bp[0];
    float4 pb1 = *(const float4*)&Bp[(size_t)32 * WROW];
    float4 pb2 = *(const float4*)&Bp[(size_t)64 * WROW];
    float4 pb3 = *(const float4*)&Bp[(size_t)96 * WROW];

    float acc[8][8];
#pragma unroll
    for (int i = 0; i < 8; ++i)
#pragma unroll
        for (int j = 0; j < 8; ++j) acc[i][j] = 0.f;

    const int nkt = KHALF / BK;
    for (int kt = 0; kt < nkt; ++kt) {
        __syncthreads();
#pragma unroll
        for (int j = 0; j < 4; ++j) {
            As[ac + j][ar]      = F4E(pa0, j);
            As[ac + j][ar + 32] = F4E(pa1, j);
            Bs[ac + j][ar]      = F4E(pb0, j);
            Bs[ac + j][ar + 32] = F4E(pb1, j);
            Bs[ac + j][ar + 64] = F4E(pb2, j);
            Bs[ac + j][ar + 96] = F4E(pb3, j);
        }
        __syncthreads();
        if (kt + 1 < nkt) {
            const float* Ap2 = Ap + (size_t)(kt + 1) * BK;
            const float* Bp2 = Bp + (size_t)(kt + 1) * BK;
            pa0 = *(const float4*)&Ap2[0];
            pa1 = *(const float4*)&Ap2[(size_t)32 * N_SIZE];
            pb0 = *(const float4*)&Bp2[0];
            pb1 = *(const float4*)&Bp2[(size_t)32 * WROW];
            pb2 = *(const float4*)&Bp2[(size_t)64 * WROW];
            pb3 = *(const float4*)&Bp2[(size_t)96 * WROW];
        }
#pragma unroll
        for (int k = 0; k < BK; ++k) {
            const float4 a0 = *(const float4*)&As[k][m0];
            const float4 a1 = *(const float4*)&As[k][m0 + 4];
            const float4 b0 = *(const float4*)&Bs[k][n0];
            const float4 b1 = *(const float4*)&Bs[k][n0 + 64];
            const float av[8] = {a0.x, a0.y, a0.z, a0.w, a1.x, a1.y, a1.z, a1.w};
            const float bv[8] = {b0.x, b0.y, b0.z, b0.w, b1.x, b1.y, b1.z, b1.w};
#pragma unroll
            for (int i = 0; i < 8; ++i)
#pragma unroll
                for (int j = 0; j < 8; ++j)
                    acc[i][j] = fmaf(av[i], bv[j], acc[i][j]);
        }
    }
#pragma unroll
    for (int i = 0; i < 8; ++i) {
        float* cp = &dst[(size_t)(bm + m0 + i) * N_SIZE + bn];
        const float4 o0 = {acc[i][0], acc[i][1], acc[i][2], acc[i][3]};
        const float4 o1 = {acc[i][4], acc[i][5], acc[i][6], acc[i][7]};
        *(float4*)&cp[n0] = o0;
        *(float4*)&cp[n0 + 64] = o1;
    }
}

__global__ __launch_bounds__(256) void k_reduce(float* __restrict__ acc,
                                                const float* __restrict__ part) {
    const size_t i = ((size_t)blockIdx.x * 256 + threadIdx.x) * 4;
    const float4 a = *(const float4*)&acc[i];
    const float4 b = *(const float4*)&part[i];
    const float4 r = {a.x + b.x, a.y + b.y, a.z + b.z, a.w + b.w};
    *(float4*)&acc[i] = r;
}

// ---------------- scan with asm-forced wide gather ----------------
// 512 thr (8 waves) * 8 neurons. The gather is 12 columns * 2
// global_load_dwordx4 issued as inline asm (compiler MUST keep ~96 VGPRs of
// results live -> all 24 loads genuinely in flight), then ONE
// s_waitcnt vmcnt(0) + sched_barrier(0). Sync = lgkmcnt(0) + raw s_barrier
// (no compiler vmcnt drain). Stores issued after barrier 2 -> no barrier
// ever waits on them; the single per-step vmcnt(0) overlaps gather +
// prefetch + previous-step stores in one latency round.
#define GL2(va, vb, ptr)                                                \
    asm volatile("global_load_dwordx4 %0, %2, off\n\t"                  \
                 "global_load_dwordx4 %1, %2, off offset:16"            \
                 : "=&v"(va), "=&v"(vb) : "v"(ptr) : "memory")

#define COL(k, sidx)                                                    \
    const float* p##k = WsT +                                           \
        (size_t)__builtin_amdgcn_readfirstlane(sidx) * N_SIZE + base;   \
    f32x4 va##k, vb##k;                                                 \
    GL2(va##k, vb##k, p##k);

#define ACC(k) { c0 += va##k; c1 += vb##k; }

#define WGSYNC()                                                        \
    do {                                                                \
        asm volatile("s_waitcnt lgkmcnt(0)" ::: "memory");              \
        __builtin_amdgcn_s_barrier();                                   \
        __builtin_amdgcn_sched_barrier(0);                              \
    } while (0)

__global__ __launch_bounds__(512, 2) void k_scanA(const float* __restrict__ WsT,
                                                  float* __restrict__ spk_out,
                                                  float* __restrict__ mem_out) {
    __shared__ int lst[2][N_SIZE + 12];
    __shared__ int wcnt[8];
    const int tid = threadIdx.x;
    const int wave = tid >> 6;
    const int lane = tid & 63;
    const int base = tid << 3;          // neurons base..base+7
    const unsigned long long below = (lane == 0) ? 0ULL : (~0ULL >> (64 - lane));

    f32x4 m0 = {0.f, 0.f, 0.f, 0.f}, m1 = {0.f, 0.f, 0.f, 0.f};
    int tot = 0;

    f32x4 cn0 = *(const f32x4*)&mem_out[base];
    f32x4 cn1 = *(const f32x4*)&mem_out[base + 4];

    for (int t = 0; t < N_STEPS; ++t) {
        f32x4 c0 = cn0, c1 = cn1;

        // prefetch next cur_x row (covered by this step's single vmcnt(0))
        const int tn = (t + 1 < N_STEPS) ? (t + 1) : t;
        const float* nr = &mem_out[(size_t)tn * N_SIZE + base];
        cn0 = *(const f32x4*)&nr[0];
        cn1 = *(const f32x4*)&nr[4];

        // ---- gather: 12 columns, 24 loads forced in flight, one wait ----
        const int* lp = lst[t & 1];
        for (int i0 = 0; i0 < tot; i0 += 12) {
            const i32x4 ia = *(const i32x4*)&lp[i0];
            const i32x4 ib = *(const i32x4*)&lp[i0 + 4];
            const i32x4 ic = *(const i32x4*)&lp[i0 + 8];
            COL(0, ia.x)  COL(1, ia.y)  COL(2, ia.z)  COL(3, ia.w)
            COL(4, ib.x)  COL(5, ib.y)  COL(6, ib.z)  COL(7, ib.w)
            COL(8, ic.x)  COL(9, ic.y)  COL(10, ic.z) COL(11, ic.w)
            asm volatile("s_waitcnt vmcnt(0)" ::: "memory");
            __builtin_amdgcn_sched_barrier(0);
            ACC(0)  ACC(1)  ACC(2)  ACC(3)  ACC(4)  ACC(5)
            ACC(6)  ACC(7)  ACC(8)  ACC(9)  ACC(10) ACC(11)
        }

        // ---- membrane update, threshold ----
        m0 += c0;
        m1 += c1;
        bool sb[8];
#pragma unroll
        for (int j = 0; j < 4; ++j) {
            sb[j] = m0[j] > THRESH;
            m0[j] -= sb[j] ? THRESH : 0.f;
            sb[4 + j] = m1[j] > THRESH;
            m1[j] -= sb[4 + j] ? THRESH : 0.f;
        }

        // ---- ballots ----
        int pre = 0, wtot = 0;
#pragma unroll
        for (int j = 0; j < 8; ++j) {
            const unsigned long long B = __ballot(sb[j]);
            pre += __popcll(B & below);
            wtot += __popcll(B);
        }
        if (lane == 0) wcnt[wave] = wtot;

        WGSYNC();   // b1: wcnt visible; all gather reads of lst[t&1] done

        int woff = 0, tt = 0;
#pragma unroll
        for (int w = 0; w < 8; ++w) {
            const int cw = wcnt[w];
            if (w < wave) woff += cw;
            tt += cw;
        }
        int* nxt = lst[(t & 1) ^ 1];
        int off = woff + pre;
#pragma unroll
        for (int j = 0; j < 8; ++j)
            if (sb[j]) nxt[off++] = base + j;
        if (tid < 12) nxt[tt + tid] = N_SIZE;   // pad -> zero row

        WGSYNC();   // b2: next list ready

        // ---- outputs AFTER barriers: no barrier ever drains them ----
        float* srow = &spk_out[(size_t)t * N_SIZE + base];
        float* mrow = &mem_out[(size_t)t * N_SIZE + base];
        const f32x4 sp0 = {sb[0] ? 1.f : 0.f, sb[1] ? 1.f : 0.f,
                           sb[2] ? 1.f : 0.f, sb[3] ? 1.f : 0.f};
        const f32x4 sp1 = {sb[4] ? 1.f : 0.f, sb[5] ? 1.f : 0.f,
                           sb[6] ? 1.f : 0.f, sb[7] ? 1.f : 0.f};
        *(f32x4*)&srow[0] = sp0;
        *(f32x4*)&srow[4] = sp1;
        *(f32x4*)&mrow[0] = m0;
        *(f32x4*)&mrow[4] = m1;

        tot = tt;
    }
}

// ---------------- fallback: single-WG scan (no/partial ws) ----------------
template <int USE_WST>
__global__ __launch_bounds__(1024) void k_scan1(const float* __restrict__ WsT,
                                                const float* __restrict__ W,
                                                float* __restrict__ spk_out,
                                                float* __restrict__ mem_out) {
    __shared__ int lists[2][N_SIZE];
    __shared__ int wcnt[16];
    const int tid = threadIdx.x;
    const int wave = tid >> 6;
    const int lane = tid & 63;
    const int base = tid << 2;
    const unsigned long long below = (lane == 0) ? 0ULL : (~0ULL >> (64 - lane));

    float4 mem = {0.f, 0.f, 0.f, 0.f};
    int cnt = 0, cur = 0;
    for (int t = 0; t < N_STEPS; ++t) {
        float* mrow = &mem_out[(size_t)t * N_SIZE + base];
        float4 c = *(const float4*)mrow;
        const int* lstp = lists[cur];
        for (int i = 0; i < cnt; ++i) {
            const int s = lstp[i];
            float4 w0;
            if (USE_WST) {
                w0 = *(const float4*)&WsT[(size_t)s * N_SIZE + base];
            } else {
                w0.x = W[(size_t)(base + 0) * WROW + N_SIZE + s];
                w0.y = W[(size_t)(base + 1) * WROW + N_SIZE + s];
                w0.z = W[(size_t)(base + 2) * WROW + N_SIZE + s];
                w0.w = W[(size_t)(base + 3) * WROW + N_SIZE + s];
            }
            ADD4(c, w0)
        }
        ADD4(mem, c)
        const bool s0 = mem.x > THRESH, s1 = mem.y > THRESH;
        const bool s2 = mem.z > THRESH, s3 = mem.w > THRESH;
        mem.x -= s0 ? THRESH : 0.f;  mem.y -= s1 ? THRESH : 0.f;
        mem.z -= s2 ? THRESH : 0.f;  mem.w -= s3 ? THRESH : 0.f;
        const float4 spkv = {s0 ? 1.f : 0.f, s1 ? 1.f : 0.f,
                             s2 ? 1.f : 0.f, s3 ? 1.f : 0.f};
        *(float4*)&spk_out[(size_t)t * N_SIZE + base] = spkv;
        *(float4*)mrow = mem;
        const unsigned long long b0 = __ballot(s0), b1 = __ballot(s1);
        const unsigned long long b2 = __ballot(s2), b3 = __ballot(s3);
        const int pre = __popcll(b0 & below) + __popcll(b1 & below) +
                        __popcll(b2 & below) + __popcll(b3 & below);
        if (lane == 0)
            wcnt[wave] = __popcll(b0) + __popcll(b1) + __popcll(b2) + __popcll(b3);
        __syncthreads();
        int woff = 0, total = 0;
#pragma unroll
        for (int wv = 0; wv < 16; ++wv) {
            const int cw = wcnt[wv];
            if (wv < wave) woff += cw;
            total += cw;
        }
        int* nxt = lists[cur ^ 1];
        int off = woff + pre;
        if (s0) nxt[off++] = base;
        if (s1) nxt[off++] = base + 1;
        if (s2) nxt[off++] = base + 2;
        if (s3) nxt[off++] = base + 3;
        __syncthreads();
        cnt = total;
        cur ^= 1;
    }
}

extern "C" void kernel_launch(void* const* d_in, const int* in_sizes, int n_in,
                              void* d_out, int out_size, void* d_ws, size_t ws_size,
                              hipStream_t stream) {
    const float* x = (const float*)d_in[0];
    const float* W = (const float*)d_in[1];
    float* spk_out = (float*)d_out;
    float* mem_out = spk_out + (size_t)N_STEPS * N_SIZE;
    float* WsT = (float*)d_ws;
    const bool full = ws_size >= WST_BYTES;
    const bool use_wst = ws_size >= (size_t)N_SIZE * N_SIZE * 4;

    if (full) {
        k_zero_row<<<16, 256, 0, stream>>>(WsT);
        k_transpose<<<dim3(N_SIZE / 32, N_SIZE / 32), dim3(32, 8), 0, stream>>>(W, WsT);
    } else if (use_wst) {
        k_transpose<<<dim3(N_SIZE / 32, N_SIZE / 32), dim3(32, 8), 0, stream>>>(W, WsT);
    }

    k_gemm<<<dim3(N_SIZE / BN, N_STEPS / BM, 2), 128, 0, stream>>>(x, W, mem_out, spk_out);
    k_reduce<<<(N_STEPS * N_SIZE) / (256 * 4), 256, 0, stream>>>(mem_out, spk_out);

    if (full) {
        k_scanA<<<1, 512, 0, stream>>>(WsT, spk_out, mem_out);
    } else if (use_wst) {
        k_scan1<1><<<1, 1024, 0, stream>>>(WsT, W, spk_out, mem_out);
    } else {
        k_scan1<0><<<1, 1024, 0, stream>>>(WsT, W, spk_out, mem_out);
    }
}